// Round 1
// 1315.828 us; speedup vs baseline: 1.0785x; 1.0785x over previous
//
#include <hip/hip_runtime.h>
#include <math.h>

#define B_ 32
#define L_ 64
#define T_ 65      // 1 + L
#define LS_ 100
#define H_ 512
#define E_ 512
#define F_ 64
#define V_ 32000
#define SOS_ 2
#define EPS_ 1e-6f

typedef __attribute__((ext_vector_type(8))) _Float16 half8;
typedef __attribute__((ext_vector_type(4))) float f32x4;

__device__ __forceinline__ float sigmoidf_(float x) { return 1.0f / (1.0f + expf(-x)); }

__device__ __forceinline__ void gload_lds16(const void* g, void* l) {
    __builtin_amdgcn_global_load_lds(
        (const __attribute__((address_space(1))) unsigned int*)g,
        (__attribute__((address_space(3))) unsigned int*)l, 16, 0, 0);
}

// ---------------------------------------------------------------------------
__global__ void build_X(const float* __restrict__ emb,
                        const float* __restrict__ inp_emb,
                        _Float16* __restrict__ X) {
    int idx = blockIdx.x * blockDim.x + threadIdx.x;
    if (idx >= T_ * B_ * E_) return;
    int e = idx % E_;
    int r = idx / E_;
    int t = r / B_, b = r % B_;
    float v;
    if (t == 0) v = emb[(size_t)SOS_ * E_ + e];
    else        v = inp_emb[((size_t)b * L_ + (t - 1)) * E_ + e];
    X[idx] = (_Float16)v;
}

__global__ void init_state(const float* __restrict__ h0, const float* __restrict__ c0,
                           float* __restrict__ h_all, float* __restrict__ c_all) {
    int idx = blockIdx.x * blockDim.x + threadIdx.x;
    if (idx < B_ * H_) { h_all[idx] = h0[idx]; c_all[idx] = c0[idx]; }
}

__global__ void convert_f16(const float* __restrict__ src, _Float16* __restrict__ dst, int n) {
    int idx = blockIdx.x * blockDim.x + threadIdx.x;
    if (idx < n) dst[idx] = (_Float16)src[idx];
}

__global__ void build_bsr(const float* __restrict__ bs, const float* __restrict__ br,
                          float* __restrict__ bsr) {
    int idx = blockIdx.x * blockDim.x + threadIdx.x;
    if (idx < H_) { bsr[idx] = bs[idx]; bsr[H_ + idx] = br[idx]; }
}

// ---------------------------------------------------------------------------
// Tiled transposes: dst[c][r] = src[r][c], src R x C row-major (R,C mult of 32)
// ---------------------------------------------------------------------------
__global__ void transpose_f32(const float* __restrict__ src, float* __restrict__ dst,
                              int R, int C) {
    __shared__ float tl[32][33];
    int r0 = blockIdx.y * 32, c0 = blockIdx.x * 32;
    int cx = threadIdx.x & 31, g = threadIdx.x >> 5;
#pragma unroll
    for (int i = 0; i < 4; i++) {
        int ry = g * 4 + i;
        tl[ry][cx] = src[(size_t)(r0 + ry) * C + c0 + cx];
    }
    __syncthreads();
#pragma unroll
    for (int i = 0; i < 4; i++) {
        int cy = g * 4 + i;
        dst[(size_t)(c0 + cy) * R + r0 + cx] = tl[cx][cy];
    }
}

__global__ void transpose_f32_to_f16(const float* __restrict__ src,
                                     _Float16* __restrict__ dst, int R, int C) {
    __shared__ float tl[32][33];
    int r0 = blockIdx.y * 32, c0 = blockIdx.x * 32;
    int cx = threadIdx.x & 31, g = threadIdx.x >> 5;
#pragma unroll
    for (int i = 0; i < 4; i++) {
        int ry = g * 4 + i;
        tl[ry][cx] = src[(size_t)(r0 + ry) * C + c0 + cx];
    }
    __syncthreads();
#pragma unroll
    for (int i = 0; i < 4; i++) {
        int cy = g * 4 + i;
        dst[(size_t)(c0 + cy) * R + r0 + cx] = (_Float16)tl[cx][cy];
    }
}

// ---------------------------------------------------------------------------
// Unified f16 MFMA GEMM (m97 structure): C = act(A[M x K](lda) @ Bt^T + bias)
// Bt is N x K row-major f16. 128x128 tile, BK=32, 4 waves 2x2, 16x16x32 MFMA,
// global_load_lds width 16. EMIT: scatter to out[(b*T+t)*V + n].
// ---------------------------------------------------------------------------
template <bool TANH, bool MASK, bool OUTF16, bool EMIT>
__global__ __launch_bounds__(256) void gemm_mfma(
        const _Float16* __restrict__ A, int lda,
        const _Float16* __restrict__ Bt,
        const float* __restrict__ bias, void* __restrict__ Cout,
        int M, int N, int K, const int* __restrict__ lens) {
    __shared__ __align__(16) _Float16 As[128 * 32];
    __shared__ __align__(16) _Float16 Bs[128 * 32];

    int bm = blockIdx.y * 128;
    int bn = blockIdx.x * 128;
    int tid = threadIdx.x;
    int wave = tid >> 6, lane = tid & 63;

    int wm = (wave & 1) * 64;
    int wn = (wave >> 1) * 64;

    f32x4 acc[4][4];
#pragma unroll
    for (int i = 0; i < 4; i++)
#pragma unroll
        for (int j = 0; j < 4; j++) acc[i][j] = (f32x4){0.f, 0.f, 0.f, 0.f};

    int srow = wave * 16 + (lane >> 2);
    int skoff = (lane & 3) * 8;

    for (int k0 = 0; k0 < K; k0 += 32) {
#pragma unroll
        for (int p = 0; p < 2; p++) {
            int r = p * 64 + srow;
            int ar = bm + r; if (ar > M - 1) ar = M - 1;
            gload_lds16(A + (size_t)ar * lda + k0 + skoff,
                        (void*)(As + (size_t)(p * 64 + wave * 16) * 32));
            gload_lds16(Bt + (size_t)(bn + r) * K + k0 + skoff,
                        (void*)(Bs + (size_t)(p * 64 + wave * 16) * 32));
        }
        __syncthreads();

        int mrow = wm + (lane & 15);
        int nrow = wn + (lane & 15);
        int kq = (lane >> 4) * 8;
        half8 afr[4], bfr[4];
#pragma unroll
        for (int i = 0; i < 4; i++)
            afr[i] = *(const half8*)&As[(mrow + i * 16) * 32 + kq];
#pragma unroll
        for (int j = 0; j < 4; j++)
            bfr[j] = *(const half8*)&Bs[(nrow + j * 16) * 32 + kq];
#pragma unroll
        for (int i = 0; i < 4; i++)
#pragma unroll
            for (int j = 0; j < 4; j++)
                acc[i][j] = __builtin_amdgcn_mfma_f32_16x16x32_f16(
                    afr[i], bfr[j], acc[i][j], 0, 0, 0);
        __syncthreads();
    }

    // C/D layout: col = lane&15, row = (lane>>4)*4 + r   [m89/m91]
    int lcol = lane & 15, lquad = lane >> 4;
#pragma unroll
    for (int i = 0; i < 4; i++) {
#pragma unroll
        for (int r = 0; r < 4; r++) {
            int gr = bm + wm + i * 16 + lquad * 4 + r;
            if (gr >= M) continue;
            bool fin = false;
            int t = gr >> 5, bb = gr & 31;
            if (MASK) fin = (t > 0) && ((t - 1) >= lens[bb]);
#pragma unroll
            for (int j = 0; j < 4; j++) {
                int gc = bn + wn + j * 16 + lcol;
                float v = acc[i][j][r] + bias[gc];
                if (TANH) v = tanhf(v);
                if (MASK && fin) v = 0.f;
                if (EMIT) {
                    ((float*)Cout)[((size_t)bb * T_ + t) * (size_t)V_ + gc] = v;
                } else if (OUTF16) {
                    ((_Float16*)Cout)[(size_t)gr * N + gc] = (_Float16)v;
                } else {
                    ((float*)Cout)[(size_t)gr * N + gc] = v;
                }
            }
        }
    }
}

// ---------------------------------------------------------------------------
// LSTM step: z = Zx[t] + h_prev @ Wh  (Wht = Wh^T precomputed f32 [2048][512])
// ---------------------------------------------------------------------------
__global__ __launch_bounds__(256) void lstm_step2(
        const float* __restrict__ Zx, const float* __restrict__ Wht,
        const int* __restrict__ lens,
        float* __restrict__ h_all, float* __restrict__ c_all,
        _Float16* __restrict__ ao_concat, int t) {
    __shared__ float Wl[16 * 516];
    __shared__ float zb[32 * 20];

    int tid = threadIdx.x;
    int j0 = blockIdx.x * 4;
    const float* h_prev = h_all + (size_t)t * B_ * H_;

    {
        int c = tid >> 4, s = tid & 15;
        int col = (c >> 2) * H_ + j0 + (c & 3);
        const float* src = Wht + (size_t)col * H_ + s * 32;
        float* dstp = Wl + c * 516 + s * 32;
#pragma unroll
        for (int i = 0; i < 8; i++)
            *(f32x4*)(dstp + i * 4) = *(const f32x4*)(src + i * 4);
    }
    __syncthreads();

    int bt = tid >> 6;
    int ct = (tid >> 4) & 3;
    int s  = tid & 15;

    float acc[8][4];
#pragma unroll
    for (int bi = 0; bi < 8; bi++)
#pragma unroll
        for (int cc = 0; cc < 4; cc++) acc[bi][cc] = 0.f;

#pragma unroll
    for (int q = 0; q < 8; q++) {
        int kbase = q * 64 + s * 4;
        f32x4 w4[4];
#pragma unroll
        for (int cc = 0; cc < 4; cc++)
            w4[cc] = *(const f32x4*)&Wl[(ct * 4 + cc) * 516 + kbase];
        f32x4 h4[8];
#pragma unroll
        for (int bi = 0; bi < 8; bi++)
            h4[bi] = *(const f32x4*)&h_prev[(size_t)(bt * 8 + bi) * H_ + kbase];
#pragma unroll
        for (int bi = 0; bi < 8; bi++)
#pragma unroll
            for (int cc = 0; cc < 4; cc++)
                acc[bi][cc] += h4[bi].x * w4[cc].x + h4[bi].y * w4[cc].y +
                               h4[bi].z * w4[cc].z + h4[bi].w * w4[cc].w;
    }

#pragma unroll
    for (int off = 8; off >= 1; off >>= 1)
#pragma unroll
        for (int bi = 0; bi < 8; bi++)
#pragma unroll
            for (int cc = 0; cc < 4; cc++)
                acc[bi][cc] += __shfl_down(acc[bi][cc], off);

    if (s == 0) {
#pragma unroll
        for (int bi = 0; bi < 8; bi++) {
            int b = bt * 8 + bi;
            f32x4 zx = *(const f32x4*)&Zx[((size_t)t * B_ + b) * (4 * H_) + ct * H_ + j0];
            f32x4 v;
            v.x = acc[bi][0] + zx.x; v.y = acc[bi][1] + zx.y;
            v.z = acc[bi][2] + zx.z; v.w = acc[bi][3] + zx.w;
            *(f32x4*)&zb[b * 20 + ct * 4] = v;
        }
    }
    __syncthreads();

    if (tid < 128) {
        int b = tid >> 2, cj = tid & 3;
        int j = j0 + cj;
        float zi = zb[b * 20 + 0 + cj];
        float zj = zb[b * 20 + 4 + cj];
        float zf = zb[b * 20 + 8 + cj];
        float zo = zb[b * 20 + 12 + cj];
        float cp = c_all[(size_t)t * B_ * H_ + (size_t)b * H_ + j];
        float hp = h_prev[(size_t)b * H_ + j];
        float c = sigmoidf_(zf + 1.0f) * cp + sigmoidf_(zi) * tanhf(zj);
        float h = sigmoidf_(zo) * tanhf(c);
        bool fin = (t > 0) && ((t - 1) >= lens[b]);
        h_all[(size_t)(t + 1) * B_ * H_ + (size_t)b * H_ + j] = fin ? hp : h;
        c_all[(size_t)(t + 1) * B_ * H_ + (size_t)b * H_ + j] = fin ? cp : c;
        ao_concat[((size_t)t * B_ + b) * 1024 + 512 + j] = (_Float16)(fin ? 0.f : h);
    }
}

// ---------------------------------------------------------------------------
// Attention: one block per (t,b) row.
//   scores: per-wave half8 dot with gamma/alpha held in registers
//   softmax: wave-parallel over 128 threads (l = tid), shfl_xor + LDS combine
//   context: 256 threads x 2 h each
// ---------------------------------------------------------------------------
__global__ __launch_bounds__(256) void attention_kernel(
        const _Float16* __restrict__ phi_hs,
        const _Float16* __restrict__ phi_fds,
        const float* __restrict__ ga,
        const float* __restrict__ enc,
        _Float16* __restrict__ ao_concat) {
    int r = blockIdx.x;
    int b = r % B_;
    int tid = threadIdx.x;
    int wave = tid >> 6, lane = tid & 63;

    __shared__ float sh[LS_], sf[LS_];
    __shared__ float red[8];

    // ---- scores: each wave handles l = wave, wave+4, ... (25 each) ----
    // gamma/alpha in registers: lane owns k = lane*8 .. lane*8+7
    const float* gw = ga + (size_t)r * 1024;
    f32x4 g0 = *(const f32x4*)&gw[lane * 8];
    f32x4 g1 = *(const f32x4*)&gw[lane * 8 + 4];
    f32x4 a0 = *(const f32x4*)&gw[512 + lane * 8];
    f32x4 a1 = *(const f32x4*)&gw[512 + lane * 8 + 4];

    const _Float16* phb = phi_hs + (size_t)b * LS_ * H_ + lane * 8;
    const _Float16* pfb = phi_fds + (size_t)b * LS_ * H_ + lane * 8;

    for (int l = wave; l < LS_; l += 4) {
        half8 ph = *(const half8*)(phb + (size_t)l * H_);
        half8 pf = *(const half8*)(pfb + (size_t)l * H_);
        float s1 = (float)ph[0] * g0.x + (float)ph[1] * g0.y +
                   (float)ph[2] * g0.z + (float)ph[3] * g0.w +
                   (float)ph[4] * g1.x + (float)ph[5] * g1.y +
                   (float)ph[6] * g1.z + (float)ph[7] * g1.w;
        float s2 = (float)pf[0] * a0.x + (float)pf[1] * a0.y +
                   (float)pf[2] * a0.z + (float)pf[3] * a0.w +
                   (float)pf[4] * a1.x + (float)pf[5] * a1.y +
                   (float)pf[6] * a1.z + (float)pf[7] * a1.w;
#pragma unroll
        for (int off = 32; off; off >>= 1) {
            s1 += __shfl_xor(s1, off);
            s2 += __shfl_xor(s2, off);
        }
        if (lane == 0) { sh[l] = s1; sf[l] = s2; }
    }
    __syncthreads();

    // ---- parallel softmax over 128 threads (tid = l) ----
    float v1 = (tid < LS_) ? sh[tid] : -1e30f;
    float v2 = (tid < LS_) ? sf[tid] : -1e30f;
    float m1 = v1, m2 = v2;
#pragma unroll
    for (int off = 32; off; off >>= 1) {
        m1 = fmaxf(m1, __shfl_xor(m1, off));
        m2 = fmaxf(m2, __shfl_xor(m2, off));
    }
    if (tid < 128 && lane == 0) { red[wave * 2] = m1; red[wave * 2 + 1] = m2; }
    __syncthreads();
    m1 = fmaxf(red[0], red[2]);
    m2 = fmaxf(red[1], red[3]);

    float e1 = (tid < LS_) ? expf(v1 - m1) : 0.f;
    float e2 = (tid < LS_) ? expf(v2 - m2) : 0.f;
    float s1 = e1, s2 = e2;
#pragma unroll
    for (int off = 32; off; off >>= 1) {
        s1 += __shfl_xor(s1, off);
        s2 += __shfl_xor(s2, off);
    }
    if (tid < 128 && lane == 0) { red[4 + wave * 2] = s1; red[4 + wave * 2 + 1] = s2; }
    __syncthreads();
    float r1 = 1.f / (EPS_ + red[4] + red[6]);
    float r2 = 1.f / (EPS_ + red[5] + red[7]);

    float w = (e1 * r1) * (e2 * r2);
    float s3 = w;
#pragma unroll
    for (int off = 32; off; off >>= 1) s3 += __shfl_xor(s3, off);
    __syncthreads();   // red[0..3] dead before rewrite
    if (tid < 128 && lane == 0) red[wave] = s3;
    __syncthreads();
    float r3 = 1.f / (EPS_ + red[0] + red[1]);
    if (tid < LS_) sh[tid] = w * r3;
    __syncthreads();

    // ---- context: each thread owns h = tid and tid+256 ----
    const float* eb = enc + (size_t)b * LS_ * H_;
    float acc0 = 0.f, acc1 = 0.f;
#pragma unroll 4
    for (int l = 0; l < LS_; l++) {
        float wl = sh[l];
        acc0 += wl * eb[(size_t)l * H_ + tid];
        acc1 += wl * eb[(size_t)l * H_ + tid + 256];
    }
    ao_concat[(size_t)r * 1024 + tid] = (_Float16)acc0;
    ao_concat[(size_t)r * 1024 + tid + 256] = (_Float16)acc1;
}

__global__ void write_final(const float* __restrict__ h_all, const float* __restrict__ c_all,
                            float* __restrict__ out) {
    int idx = blockIdx.x * blockDim.x + threadIdx.x;
    if (idx < B_ * H_) {
        size_t base = (size_t)B_ * T_ * V_;
        out[base + idx] = h_all[(size_t)T_ * B_ * H_ + idx];
        out[base + B_ * H_ + idx] = c_all[(size_t)T_ * B_ * H_ + idx];
    }
}

extern "C" void kernel_launch(void* const* d_in, const int* in_sizes, int n_in,
                              void* d_out, int out_size, void* d_ws, size_t ws_size,
                              hipStream_t stream) {
    const float* h0   = (const float*)d_in[0];
    const float* c0   = (const float*)d_in[1];
    const float* inp_emb = (const float*)d_in[2];
    const float* enc  = (const float*)d_in[3];
    const float* fld  = (const float*)d_in[4];
    const float* emb  = (const float*)d_in[5];
    const float* lstm_W = (const float*)d_in[6];
    const float* lstm_b = (const float*)d_in[7];
    const float* Wh = (const float*)d_in[8];
    const float* bh = (const float*)d_in[9];
    const float* Ws = (const float*)d_in[10];
    const float* bs = (const float*)d_in[11];
    const float* Wr = (const float*)d_in[12];
    const float* br = (const float*)d_in[13];
    const float* Wf = (const float*)d_in[14];
    const float* bfp = (const float*)d_in[15];
    const float* Wo = (const float*)d_in[16];
    const float* bo = (const float*)d_in[17];
    const float* out_W = (const float*)d_in[18];
    const float* out_b = (const float*)d_in[19];
    const int*   lens  = (const int*)d_in[20];
    float* out = (float*)d_out;

    char* p = (char*)d_ws;
    auto alloc = [&](size_t bytes) { char* r = p; p += (bytes + 255) & ~(size_t)255; return r; };

    // --- alias region (all dead before out_W transpose) ---
    char* region = p;
    float*    Zx    = (float*)   alloc((size_t)T_ * B_ * 4 * H_ * 4);  // 17.04 MB
    float*    ga    = (float*)   alloc((size_t)T_ * B_ * 1024 * 4);    //  8.52 MB
    _Float16* X_h   = (_Float16*)alloc((size_t)T_ * B_ * E_ * 2);      //  2.13 MB
    _Float16* enc_h = (_Float16*)alloc((size_t)B_ * LS_ * H_ * 2);     //  3.28 MB
    _Float16* Wxt_h = (_Float16*)alloc((size_t)4 * H_ * E_ * 2);       //  2.10 MB
    _Float16* Wt_h  = (_Float16*)region;  // 32000x512 f16 = 32.77 MB <= 33.07 MB
    // --- persistent ---
    _Float16* phi_hs_h  = (_Float16*)alloc((size_t)B_ * LS_ * H_ * 2);
    _Float16* phi_fds_h = (_Float16*)alloc((size_t)B_ * LS_ * H_ * 2);
    float*    h_all = (float*)alloc((size_t)(T_ + 1) * B_ * H_ * 4);
    float*    c_all = (float*)alloc((size_t)(T_ + 1) * B_ * H_ * 4);
    _Float16* ao_h  = (_Float16*)alloc((size_t)T_ * B_ * 1024 * 2);
    float*    Wht   = (float*)alloc((size_t)4 * H_ * H_ * 4);
    _Float16* fld_h = (_Float16*)alloc((size_t)B_ * LS_ * F_ * 2);
    _Float16* Wh_t  = (_Float16*)alloc((size_t)H_ * H_ * 2);
    _Float16* Wsr_t = (_Float16*)alloc((size_t)1024 * H_ * 2);
    _Float16* Wo_t  = (_Float16*)alloc((size_t)H_ * 1024 * 2);
    _Float16* Wf_t  = (_Float16*)alloc((size_t)H_ * F_ * 2);
    _Float16* att_h = (_Float16*)alloc((size_t)T_ * B_ * H_ * 2);
    float*    bsr   = (float*)alloc(1024 * 4);

    // ---- setup / conversions ----
    build_X<<<(T_ * B_ * E_ + 255) / 256, 256, 0, stream>>>(emb, inp_emb, X_h);
    init_state<<<(B_ * H_ + 255) / 256, 256, 0, stream>>>(h0, c0, h_all, c_all);
    build_bsr<<<2, 256, 0, stream>>>(bs, br, bsr);
    convert_f16<<<(B_ * LS_ * H_ + 255) / 256, 256, 0, stream>>>(enc, enc_h, B_ * LS_ * H_);
    convert_f16<<<(B_ * LS_ * F_ + 255) / 256, 256, 0, stream>>>(fld, fld_h, B_ * LS_ * F_);
    {   // Wht f32 = lstm_W[E:,:]^T ; Wxt_h f16 = lstm_W[:E,:]^T
        dim3 g(4 * H_ / 32, H_ / 32);
        transpose_f32<<<g, 256, 0, stream>>>(lstm_W + (size_t)E_ * 4 * H_, Wht, H_, 4 * H_);
        transpose_f32_to_f16<<<g, 256, 0, stream>>>(lstm_W, Wxt_h, E_, 4 * H_);
    }
    {   dim3 g(H_ / 32, H_ / 32);
        transpose_f32_to_f16<<<g, 256, 0, stream>>>(Wh, Wh_t, H_, H_);
        transpose_f32_to_f16<<<g, 256, 0, stream>>>(Ws, Wsr_t, H_, H_);
        transpose_f32_to_f16<<<g, 256, 0, stream>>>(Wr, Wsr_t + (size_t)H_ * H_, H_, H_);
    }
    {   dim3 g(H_ / 32, F_ / 32);
        transpose_f32_to_f16<<<g, 256, 0, stream>>>(Wf, Wf_t, F_, H_);
    }
    {   dim3 g(H_ / 32, 1024 / 32);
        transpose_f32_to_f16<<<g, 256, 0, stream>>>(Wo, Wo_t, 1024, H_);
    }

    // ---- feedforward GEMMs (f16 MFMA) ----
    // Zx = X @ lstm_W[:E] + lstm_b   (f32 out, needed by recurrence)
    {   dim3 g(2048 / 128, (T_ * B_ + 127) / 128);
        gemm_mfma<false, false, false, false><<<g, 256, 0, stream>>>(
            X_h, E_, Wxt_h, lstm_b, Zx, T_ * B_, 2048, 512, nullptr);
    }
    // phi_hs = tanh(enc @ Wh + bh); phi_fds = tanh(fld @ Wf + bf)
    {   dim3 g(512 / 128, 3200 / 128);
        gemm_mfma<true, false, true, false><<<g, 256, 0, stream>>>(
            enc_h, H_, Wh_t, bh, phi_hs_h, B_ * LS_, 512, 512, nullptr);
        gemm_mfma<true, false, true, false><<<g, 256, 0, stream>>>(
            fld_h, F_, Wf_t, bfp, phi_fds_h, B_ * LS_, 512, 64, nullptr);
    }
    // ---- sequential LSTM chain ----
    for (int t = 0; t < T_; t++) {
        lstm_step2<<<128, 256, 0, stream>>>(Zx, Wht, lens, h_all, c_all, ao_h, t);
    }
    // ga = tanh(o_t @ [Ws|Wr] + [bs|br])   (2080 x 1024 x 512, f32 out)
    {   dim3 g(1024 / 128, (T_ * B_ + 127) / 128);
        gemm_mfma<true, false, false, false><<<g, 256, 0, stream>>>(
            ao_h + 512, 1024, Wsr_t, bsr, ga, T_ * B_, 1024, 512, nullptr);
    }
    attention_kernel<<<T_ * B_, 256, 0, stream>>>(phi_hs_h, phi_fds_h, ga, enc, ao_h);
    // Wt_h = out_W^T f16 (aliases Zx/ga/X_h/enc_h/Wxt_h — all dead now)
    {   dim3 g(V_ / 32, 512 / 32);
        transpose_f32_to_f16<<<g, 256, 0, stream>>>(out_W, Wt_h, 512, V_);
    }
    // att = tanh([context|o_t] @ Wo + bo), masked, f16 out
    {   dim3 g(512 / 128, (T_ * B_ + 127) / 128);
        gemm_mfma<true, true, true, false><<<g, 256, 0, stream>>>(
            ao_h, 1024, Wo_t, bo, att_h, T_ * B_, 512, 1024, lens);
    }
    // logits = att @ out_W + out_b, masked, emit-scatter
    {   dim3 g(V_ / 128, (T_ * B_ + 127) / 128);
        gemm_mfma<false, true, false, true><<<g, 256, 0, stream>>>(
            att_h, H_, Wt_h, out_b, out, T_ * B_, V_, 512, lens);
    }
    write_final<<<(B_ * H_ + 255) / 256, 256, 0, stream>>>(h_all, c_all, out);
}